// Round 8
// baseline (17964.771 us; speedup 1.0000x reference)
//
#include <hip/hip_runtime.h>

#define T_STEPS 4096
#define DIN     512
#define R_DIM   4096
#define DOUT    512
#define NINT    (R_DIM + DIN)   // 4608
#define NBLK    256
#define NTHR    512
#define NSLOT   2048            // 16B LL slots per buffer; slot s = cols {2s,2s+1}
#define LEAKF   0.9f

typedef float f32x4 __attribute__((ext_vector_type(4)));
typedef unsigned int u32;
typedef u32 u32x4 __attribute__((ext_vector_type(4)));

// tanh via hardware exp2: tanh(x) = 1 - 2/(1 + e^{2x})
__device__ __forceinline__ float fast_tanh(float x)
{
    float e = __builtin_amdgcn_exp2f(x * 2.885390081777927f);
    return 1.0f - 2.0f * __builtin_amdgcn_rcpf(1.0f + e);
}

// Butterfly reduce of TWO values across 64 lanes: even lanes end with full
// sum of a0, odd lanes full sum of a1.
__device__ __forceinline__ float wave_reduce2(float a0, float a1, int lane)
{
    a0 += __shfl_xor(a0, 1);
    a1 += __shfl_xor(a1, 1);
    float b = (lane & 1) ? a1 : a0;
    b += __shfl_xor(b, 2);
    b += __shfl_xor(b, 4);
    b += __shfl_xor(b, 8);
    b += __shfl_xor(b, 16);
    b += __shfl_xor(b, 32);
    return b;
}

// ---------------------------------------------------------------------------
// Persistent fused ESN: r5 consumer structure (thread owns the 8 input
// columns it polls -> matvec from poll registers BEFORE any block sync, so
// compute overlaps straggler wait) + r7 AGPR-resident weights (the fix for
// what actually sank r5: weights streaming from L2 inside the critical
// matvec). 256 blocks x 512 threads, 1 block/CU.
// Block b owns output rows [16b,16b+16). Thread tid owns input columns
// [8tid, 8tid+8) = LL slots [4tid, 4tid+4).
// AGPRs: aw[r*8+c] = Wres[16b+r][8*tid+c]  (128 AGPRs, volatile accvgpr).
// ---------------------------------------------------------------------------
__global__ __launch_bounds__(NTHR, 2) void esn_fused(
    const float* __restrict__ x,       // (T, DIN)
    const float* __restrict__ Win_w,   // (R, DIN)
    const float* __restrict__ Win_b,   // (R)
    const float* __restrict__ Wres,    // (R, R)
    const float* __restrict__ Wout_w,  // (DOUT, NINT)
    const float* __restrict__ Wout_b,  // (DOUT)
    float* __restrict__ y,             // (T, DOUT)
    u32x4* __restrict__ comm)          // 2 * NSLOT slots (d_ws)
{
    const int tid  = threadIdx.x;
    const int wave = tid >> 6;
    const int lane = tid & 63;
    const int bid  = blockIdx.x;

    __shared__ float s_lds[R_DIM];          // 16 KB: s_{i-1} (readout + s_old)
    __shared__ float wout_lds[2 * NINT];    // 36.9 KB
    __shared__ float red[8][16];            // matvec cross-wave partials
    __shared__ float red2[8][2];            // readout partials
    __shared__ float u_lds[2][16];          // proj incl. bias, double-buffered

    // ---- one-time staging ----
    {
        const float* wsrc = Wout_w + (size_t)(bid << 1) * NINT;
        for (int idx = tid; idx < 2 * NINT; idx += NTHR)
            wout_lds[idx] = wsrc[idx];
    }
    const float wb = (tid < 2) ? Wout_b[(bid << 1) + tid] : 0.f;

    // ---- Wres into AGPRs: 16 block rows x this thread's 8 columns ----
    float aw[128];
    {
        const float* wp = Wres + (size_t)(bid << 4) * R_DIM + (tid << 3);
#pragma unroll
        for (int r = 0; r < 16; ++r) {
            f32x4 v0 = *(const f32x4*)(wp + (size_t)r * R_DIM);
            f32x4 v1 = *(const f32x4*)(wp + (size_t)r * R_DIM + 4);
#pragma unroll
            for (int q = 0; q < 4; ++q) {
                asm volatile("v_accvgpr_write_b32 %0, %1"
                             : "=a"(aw[(r << 3) + q]) : "v"(v0[q]));
                asm volatile("v_accvgpr_write_b32 %0, %1"
                             : "=a"(aw[(r << 3) + 4 + q]) : "v"(v1[q]));
            }
        }
    }

    // ---- Win: wave w owns rows {16b+2w, 16b+2w+1} over full DIN (proj) ----
    const int row_e = (bid << 4) + (wave << 1);
    f32x4 win[2][2];
    {
        const float* ip = Win_w + (size_t)row_e * DIN + (lane << 2);
#pragma unroll
        for (int r = 0; r < 2; ++r)
#pragma unroll
            for (int c = 0; c < 2; ++c)
                win[r][c] = *(const f32x4*)(ip + (size_t)r * DIN + (c << 8));
    }
    const float bias_e = Win_b[row_e];
    const float bias_o = Win_b[row_e + 1];

    float a0, a1;
#define PROJ(xrow)                                                        \
    {                                                                     \
        f32x4 xv0 = *(const f32x4*)((xrow) + (lane << 2));                \
        f32x4 xv1 = *(const f32x4*)((xrow) + 256 + (lane << 2));          \
        a0 = 0.f; a1 = 0.f;                                               \
        _Pragma("unroll")                                                 \
        for (int q = 0; q < 4; ++q) {                                     \
            a0 += win[0][0][q] * xv0[q] + win[0][1][q] * xv1[q];          \
            a1 += win[1][0][q] * xv0[q] + win[1][1][q] * xv1[q];          \
        }                                                                 \
    }

    // ---- step 0: s0 = tanh(Win x0 + b); wave-autonomous publish, tag 1 ----
    {
        PROJ(x);
        float b = wave_reduce2(a0, a1, lane);
        float se = __shfl(b, 0) + bias_e;
        float so = __shfl(b, 1) + bias_o;
        if (lane == 0) {
            u32x4 pkt;
            pkt.x = __float_as_uint(fast_tanh(se)); pkt.y = 1u;
            pkt.z = __float_as_uint(fast_tanh(so)); pkt.w = 1u;
            u32x4* dst = comm + (bid << 3) + wave;
            asm volatile("global_store_dwordx4 %0, %1, off sc0 sc1"
                         :: "v"(dst), "v"(pkt) : "memory");
        }
    }
    // ---- proj(1) -> u_lds[1] ----
    {
        PROJ(x + DIN);
        float b = wave_reduce2(a0, a1, lane);
        if (lane < 2)
            u_lds[1][(wave << 1) + lane] = b + (lane ? bias_o : bias_e);
    }

    for (int i = 1; i <= T_STEPS; ++i) {
        // ---- incremental LL poll of own 4 slots (tag = i) ----
        u32x4 q0 = {0,0,0,0}, q1 = {0,0,0,0}, q2 = {0,0,0,0}, q3 = {0,0,0,0};
        {
            const u32x4* src = comm + (((i - 1) & 1) * NSLOT) + (tid << 2);
            const u32 tag = (u32)i;
            u32 pend = 0xFu;
            for (;;) {
                if (pend & 1u)
                    asm volatile("global_load_dwordx4 %0, %1, off sc0 sc1"
                                 : "=&v"(q0) : "v"(src) : "memory");
                if (pend & 2u)
                    asm volatile("global_load_dwordx4 %0, %1, off sc0 sc1"
                                 : "=&v"(q1) : "v"(src + 1) : "memory");
                if (pend & 4u)
                    asm volatile("global_load_dwordx4 %0, %1, off sc0 sc1"
                                 : "=&v"(q2) : "v"(src + 2) : "memory");
                if (pend & 8u)
                    asm volatile("global_load_dwordx4 %0, %1, off sc0 sc1"
                                 : "=&v"(q3) : "v"(src + 3) : "memory");
                asm volatile("s_waitcnt vmcnt(0)" ::: "memory");
                if ((q0.y == tag) & (q0.w == tag)) pend &= ~1u;
                if ((q1.y == tag) & (q1.w == tag)) pend &= ~2u;
                if ((q2.y == tag) & (q2.w == tag)) pend &= ~4u;
                if ((q3.y == tag) & (q3.w == tag)) pend &= ~8u;
                if (!pend) break;
                __builtin_amdgcn_s_sleep(1);
            }
        }
        f32x4 sv0, sv1;
        sv0[0] = __uint_as_float(q0.x); sv0[1] = __uint_as_float(q0.z);
        sv0[2] = __uint_as_float(q1.x); sv0[3] = __uint_as_float(q1.z);
        sv1[0] = __uint_as_float(q2.x); sv1[1] = __uint_as_float(q2.z);
        sv1[2] = __uint_as_float(q3.x); sv1[3] = __uint_as_float(q3.z);
        // stage for readout / s_old (hides under FMAs)
        *(f32x4*)&s_lds[tid << 3] = sv0;
        *(f32x4*)&s_lds[(tid << 3) + 4] = sv1;

        if (i < T_STEPS) {
            // ---- matvec from poll registers, weights from AGPRs ----
            float p[16];
#pragma unroll
            for (int r = 0; r < 16; ++r) {
                float acc_a = 0.f, acc_b = 0.f;
#pragma unroll
                for (int q = 0; q < 4; ++q) {
                    float t0, t1;
                    asm volatile("v_accvgpr_read_b32 %0, %1"
                                 : "=v"(t0) : "a"(aw[(r << 3) + q]));
                    asm volatile("v_accvgpr_read_b32 %0, %1"
                                 : "=v"(t1) : "a"(aw[(r << 3) + 4 + q]));
                    acc_a += t0 * sv0[q];
                    acc_b += t1 * sv1[q];
                }
                p[r] = acc_a + acc_b;
            }
            // ---- in-wave 16-value butterfly: lane l ends with row (l&15) ----
#pragma unroll
            for (int j = 0; j < 8; ++j) {
                float a = p[2*j], b = p[2*j+1];
                a += __shfl_xor(a, 1); b += __shfl_xor(b, 1);
                p[j] = (lane & 1) ? b : a;
            }
#pragma unroll
            for (int j = 0; j < 4; ++j) {
                float a = p[2*j], b = p[2*j+1];
                a += __shfl_xor(a, 2); b += __shfl_xor(b, 2);
                p[j] = (lane & 2) ? b : a;
            }
#pragma unroll
            for (int j = 0; j < 2; ++j) {
                float a = p[2*j], b = p[2*j+1];
                a += __shfl_xor(a, 4); b += __shfl_xor(b, 4);
                p[j] = (lane & 4) ? b : a;
            }
            {
                float a = p[0], b = p[1];
                a += __shfl_xor(a, 8); b += __shfl_xor(b, 8);
                p[0] = (lane & 8) ? b : a;
            }
            p[0] += __shfl_xor(p[0], 16);
            p[0] += __shfl_xor(p[0], 32);
            if (lane < 16) red[wave][lane] = p[0];
        }
        __syncthreads();

        // ---- wave 0 finalizes + publishes (tag i+1) ----
        if (i < T_STEPS && wave == 0) {
            float tot = 0.f;
            if (lane < 16) {
#pragma unroll
                for (int wv = 0; wv < 8; ++wv) tot += red[wv][lane];
                tot += u_lds[i & 1][lane];
                float s_old = s_lds[(bid << 4) + lane];
                tot = (1.f - LEAKF) * s_old + LEAKF * fast_tanh(tot);
            }
            float e = __shfl(tot, (lane & 7) << 1);
            float o = __shfl(tot, ((lane & 7) << 1) + 1);
            if (lane < 8) {
                u32 t2 = (u32)(i + 1);
                u32x4 pkt;
                pkt.x = __float_as_uint(e); pkt.y = t2;
                pkt.z = __float_as_uint(o); pkt.w = t2;
                u32x4* dst = comm + ((i & 1) * NSLOT) + (bid << 3) + lane;
                asm volatile("global_store_dwordx4 %0, %1, off sc0 sc1"
                             :: "v"(dst), "v"(pkt) : "memory");
            }
        }

        // ---- overlapped: readout y[i-1] partials ----
        {
            float xv = x[(size_t)(i - 1) * DIN + tid];
            float y0 = wout_lds[tid] * xv;
            float y1 = wout_lds[NINT + tid] * xv;
#pragma unroll
            for (int j = 0; j < 8; ++j) {
                float sv = s_lds[tid + j * NTHR];
                y0 += wout_lds[DIN + tid + j * NTHR] * sv;
                y1 += wout_lds[NINT + DIN + tid + j * NTHR] * sv;
            }
            float b = wave_reduce2(y0, y1, lane);
            if (lane < 2) red2[wave][lane] = b;
        }

        // ---- overlapped: proj(i+1) -> u_lds[(i+1)&1] ----
        if (i + 1 < T_STEPS) {
            PROJ(x + (size_t)(i + 1) * DIN);
            float b = wave_reduce2(a0, a1, lane);
            if (lane < 2)
                u_lds[(i + 1) & 1][(wave << 1) + lane] = b + (lane ? bias_o : bias_e);
        }

        __syncthreads();   // red2/u_lds complete; s_lds reads done

        if (tid < 2) {
            float s = 0.f;
#pragma unroll
            for (int wv = 0; wv < 8; ++wv) s += red2[wv][tid];
            y[(size_t)(i - 1) * DOUT + (bid << 1) + tid] = s + wb;
        }
    }
#undef PROJ
}

extern "C" void kernel_launch(void* const* d_in, const int* in_sizes, int n_in,
                              void* d_out, int out_size, void* d_ws, size_t ws_size,
                              hipStream_t stream) {
    const float* x      = (const float*)d_in[0];
    const float* Win_w  = (const float*)d_in[1];
    const float* Win_b  = (const float*)d_in[2];
    const float* Wres_w = (const float*)d_in[3];
    const float* Wout_w = (const float*)d_in[4];
    const float* Wout_b = (const float*)d_in[5];
    float* yp = (float*)d_out;

    u32x4* comm = (u32x4*)d_ws;   // 2 * 2048 slots * 16 B = 64 KB

    hipMemsetAsync(d_ws, 0, 2 * NSLOT * sizeof(u32x4), stream);

    void* args[] = { (void*)&x, (void*)&Win_w, (void*)&Win_b, (void*)&Wres_w,
                     (void*)&Wout_w, (void*)&Wout_b, (void*)&yp, (void*)&comm };
    hipLaunchCooperativeKernel((void*)esn_fused, dim3(NBLK), dim3(NTHR),
                               args, 0, stream);
}

// Round 9
// 10337.908 us; speedup vs baseline: 1.7378x; 1.7378x over previous
//
#include <hip/hip_runtime.h>

#define T_STEPS 4096
#define DIN     512
#define R_DIM   4096
#define DOUT    512
#define NINT    (R_DIM + DIN)   // 4608
#define NBLK    256
#define NTHR    512
#define NUNIT   2048            // 8B LL units per buffer; unit u = rows {2u,2u+1} bf16
#define LEAKF   0.9f

typedef float f32x4 __attribute__((ext_vector_type(4)));
typedef unsigned int u32;
typedef u32 u32x2 __attribute__((ext_vector_type(2)));

// tanh via hardware exp2: tanh(x) = 1 - 2/(1 + e^{2x})
__device__ __forceinline__ float fast_tanh(float x)
{
    float e = __builtin_amdgcn_exp2f(x * 2.885390081777927f);
    return 1.0f - 2.0f * __builtin_amdgcn_rcpf(1.0f + e);
}

__device__ __forceinline__ u32 f2bf(float f)   // RNE f32 -> bf16 bits
{
    u32 u = __float_as_uint(f);
    return (u + 0x7FFFu + ((u >> 16) & 1u)) >> 16;
}

// Butterfly reduce of TWO values across 64 lanes: even lanes end with full
// sum of a0, odd lanes full sum of a1.
__device__ __forceinline__ float wave_reduce2(float a0, float a1, int lane)
{
    a0 += __shfl_xor(a0, 1);
    a1 += __shfl_xor(a1, 1);
    float b = (lane & 1) ? a1 : a0;
    b += __shfl_xor(b, 2);
    b += __shfl_xor(b, 4);
    b += __shfl_xor(b, 8);
    b += __shfl_xor(b, 16);
    b += __shfl_xor(b, 32);
    return b;
}

// ---------------------------------------------------------------------------
// Persistent fused ESN, r4 skeleton + bf16 LL exchange + single barrier/step.
// 256 blocks x 512 threads (cooperative, 1 block/CU). Block b owns rows
// [16b,16b+16); wave w owns rows {16b+2w,16b+2w+1} over the FULL K range and
// publishes its own 8B LL unit {bf16 e, bf16 o, u32 tag} autonomously.
// s_lds is parity double-buffered so only ONE __syncthreads per step is
// needed; the readout is done by waves 0,1 as complete y-rows (no cross-wave
// reduction, no second barrier).
// ---------------------------------------------------------------------------
__global__ __launch_bounds__(NTHR, 2) void esn_fused(
    const float* __restrict__ x,       // (T, DIN)
    const float* __restrict__ Win_w,   // (R, DIN)
    const float* __restrict__ Win_b,   // (R)
    const float* __restrict__ Wres,    // (R, R)
    const float* __restrict__ Wout_w,  // (DOUT, NINT)
    const float* __restrict__ Wout_b,  // (DOUT)
    float* __restrict__ y,             // (T, DOUT)
    u32x2* __restrict__ comm)          // 2 * NUNIT units (d_ws)
{
    const int tid  = threadIdx.x;
    const int wave = tid >> 6;
    const int lane = tid & 63;
    const int bid  = blockIdx.x;
    const int row_e = (bid << 4) + (wave << 1);

    __shared__ float s_lds[2][R_DIM];       // 32 KB, parity double-buffer
    __shared__ float wout_lds[2 * NINT];    // 36.9 KB

    // ---- one-time staging ----
    {
        const float* wsrc = Wout_w + (size_t)(bid << 1) * NINT;
        for (int idx = tid; idx < 2 * NINT; idx += NTHR)
            wout_lds[idx] = wsrc[idx];
    }
    float wb = 0.f;
    if (wave < 2 && lane == 0) wb = Wout_b[(bid << 1) + wave];

    // Wres rows: w[r][c] = Wres[row_e+r][lane*4 + c*256 .. +3]
    f32x4 w[2][16];
    {
        const float* wp = Wres + (size_t)row_e * R_DIM + (lane << 2);
#pragma unroll
        for (int r = 0; r < 2; ++r)
#pragma unroll
            for (int c = 0; c < 16; ++c)
                w[r][c] = *(const f32x4*)(wp + (size_t)r * R_DIM + (c << 8));
    }
    f32x4 win[2][2];
    {
        const float* ip = Win_w + (size_t)row_e * DIN + (lane << 2);
#pragma unroll
        for (int r = 0; r < 2; ++r)
#pragma unroll
            for (int c = 0; c < 2; ++c)
                win[r][c] = *(const f32x4*)(ip + (size_t)r * DIN + (c << 8));
    }
    const float bias_e = Win_b[row_e];
    const float bias_o = Win_b[row_e + 1];
    float s_old_e = 0.f, s_old_o = 0.f;

    float a0, a1;

#define PROJ(xrow)                                                        \
    {                                                                     \
        f32x4 xv0 = *(const f32x4*)((xrow) + (lane << 2));                \
        f32x4 xv1 = *(const f32x4*)((xrow) + 256 + (lane << 2));          \
        a0 = 0.f; a1 = 0.f;                                               \
        _Pragma("unroll")                                                 \
        for (int q = 0; q < 4; ++q) {                                     \
            a0 += win[0][0][q] * xv0[q] + win[0][1][q] * xv1[q];          \
            a1 += win[1][0][q] * xv0[q] + win[1][1][q] * xv1[q];          \
        }                                                                 \
    }

#define PUBLISH(sn_e, sn_o, tagv, bufsel)                                 \
    if (lane == 0) {                                                      \
        u32x2 pkt;                                                        \
        pkt.x = f2bf(sn_e) | (f2bf(sn_o) << 16);                          \
        pkt.y = (u32)(tagv);                                              \
        u32x2* dst = comm + ((bufsel) * NUNIT) + (bid << 3) + wave;       \
        asm volatile("global_store_dwordx2 %0, %1, off sc0 sc1"           \
                     :: "v"(dst), "v"(pkt) : "memory");                   \
    }

    // ---- step 0: s0 = tanh(Win x0 + b); publish tag 1, buffer 0 ----
    {
        PROJ(x);
        float b = wave_reduce2(a0, a1, lane);
        float se = __shfl(b, 0) + bias_e;
        float so = __shfl(b, 1) + bias_o;
        float sn_e = fast_tanh(se);
        float sn_o = fast_tanh(so);
        s_old_e = sn_e; s_old_o = sn_o;
        PUBLISH(sn_e, sn_o, 1u, 0);
    }
    PROJ(x + DIN);   // proj(1)

    for (int i = 1; i <= T_STEPS; ++i) {
        const int p = (i - 1) & 1;

        // ---- poll own 4 LL units (tag = i), single round trip ----
        {
            const u32x2* src = comm + (p * NUNIT) + (tid << 2);
            const u32 tag = (u32)i;
            u32x2 q0, q1, q2, q3;
            for (;;) {
                asm volatile("global_load_dwordx2 %0, %4, off sc0 sc1\n\t"
                             "global_load_dwordx2 %1, %5, off sc0 sc1\n\t"
                             "global_load_dwordx2 %2, %6, off sc0 sc1\n\t"
                             "global_load_dwordx2 %3, %7, off sc0 sc1\n\t"
                             "s_waitcnt vmcnt(0)"
                             : "=&v"(q0), "=&v"(q1), "=&v"(q2), "=&v"(q3)
                             : "v"(src), "v"(src + 1), "v"(src + 2), "v"(src + 3)
                             : "memory");
                u32 ok = (q0.y == tag) & (q1.y == tag) &
                         (q2.y == tag) & (q3.y == tag);
                if (ok) break;
                __builtin_amdgcn_s_sleep(1);
            }
            // unpack 8 bf16 -> f32, stage into s_lds[p][8tid .. 8tid+7]
            f32x4 lo, hi;
            lo[0] = __uint_as_float((q0.x & 0xFFFFu) << 16);
            lo[1] = __uint_as_float(q0.x & 0xFFFF0000u);
            lo[2] = __uint_as_float((q1.x & 0xFFFFu) << 16);
            lo[3] = __uint_as_float(q1.x & 0xFFFF0000u);
            hi[0] = __uint_as_float((q2.x & 0xFFFFu) << 16);
            hi[1] = __uint_as_float(q2.x & 0xFFFF0000u);
            hi[2] = __uint_as_float((q3.x & 0xFFFFu) << 16);
            hi[3] = __uint_as_float(q3.x & 0xFFFF0000u);
            *(f32x4*)&s_lds[p][tid << 3] = lo;
            *(f32x4*)&s_lds[p][(tid << 3) + 4] = hi;
        }
        __syncthreads();   // the ONLY barrier per step

        if (i < T_STEPS) {
            // ---- matvec: s from LDS (16 x b128), accumulate onto proj ----
            const f32x4* s4 = (const f32x4*)&s_lds[p][0] + lane;
#pragma unroll
            for (int c = 0; c < 16; ++c) {
                f32x4 sv = s4[c << 6];
#pragma unroll
                for (int q = 0; q < 4; ++q) {
                    a0 += w[0][c][q] * sv[q];
                    a1 += w[1][c][q] * sv[q];
                }
            }
            float b = wave_reduce2(a0, a1, lane);
            float se = __shfl(b, 0) + bias_e;
            float so = __shfl(b, 1) + bias_o;
            float sn_e = (1.f - LEAKF) * s_old_e + LEAKF * fast_tanh(se);
            float sn_o = (1.f - LEAKF) * s_old_o + LEAKF * fast_tanh(so);
            s_old_e = sn_e; s_old_o = sn_o;
            PUBLISH(sn_e, sn_o, (u32)(i + 1), i & 1);
        }

        // ---- readout y[i-1]: waves 0,1 each compute one FULL row ----
        if (wave < 2) {
            const float* wrow = wout_lds + wave * NINT;
            float acc = 0.f;
            {   // x part: lane covers 8 of 512
                const float* xr = x + (size_t)(i - 1) * DIN + (lane << 3);
                f32x4 xa = *(const f32x4*)xr;
                f32x4 xb = *(const f32x4*)(xr + 4);
                const f32x4* wr4 = (const f32x4*)wrow + (lane << 1);
                f32x4 wa = wr4[0], wbv = wr4[1];
#pragma unroll
                for (int q = 0; q < 4; ++q)
                    acc += xa[q] * wa[q] + xb[q] * wbv[q];
            }
            {   // s part: 16 x b128 over the 4096 states
                const f32x4* s4 = (const f32x4*)&s_lds[p][0] + lane;
                const f32x4* wr4 = (const f32x4*)(wrow + DIN) + lane;
#pragma unroll
                for (int c = 0; c < 16; ++c) {
                    f32x4 sv = s4[c << 6];
                    f32x4 wv = wr4[c << 6];
#pragma unroll
                    for (int q = 0; q < 4; ++q)
                        acc += sv[q] * wv[q];
                }
            }
            acc += __shfl_xor(acc, 1);
            acc += __shfl_xor(acc, 2);
            acc += __shfl_xor(acc, 4);
            acc += __shfl_xor(acc, 8);
            acc += __shfl_xor(acc, 16);
            acc += __shfl_xor(acc, 32);
            if (lane == 0)
                y[(size_t)(i - 1) * DOUT + (bid << 1) + wave] = acc + wb;
        }

        // ---- proj(i+1) -> fresh a0,a1 for next matvec ----
        if (i + 1 < T_STEPS) PROJ(x + (size_t)(i + 1) * DIN);
    }
#undef PROJ
#undef PUBLISH
}

extern "C" void kernel_launch(void* const* d_in, const int* in_sizes, int n_in,
                              void* d_out, int out_size, void* d_ws, size_t ws_size,
                              hipStream_t stream) {
    const float* x      = (const float*)d_in[0];
    const float* Win_w  = (const float*)d_in[1];
    const float* Win_b  = (const float*)d_in[2];
    const float* Wres_w = (const float*)d_in[3];
    const float* Wout_w = (const float*)d_in[4];
    const float* Wout_b = (const float*)d_in[5];
    float* yp = (float*)d_out;

    u32x2* comm = (u32x2*)d_ws;   // 2 * 2048 units * 8 B = 32 KB

    hipMemsetAsync(d_ws, 0, 2 * NUNIT * sizeof(u32x2), stream);

    void* args[] = { (void*)&x, (void*)&Win_w, (void*)&Win_b, (void*)&Wres_w,
                     (void*)&Wout_w, (void*)&Wout_b, (void*)&yp, (void*)&comm };
    hipLaunchCooperativeKernel((void*)esn_fused, dim3(NBLK), dim3(NTHR),
                               args, 0, stream);
}